// Round 20
// baseline (105.844 us; speedup 1.0000x reference)
//
#include <hip/hip_runtime.h>
#include <math.h>

// Fused fab_penalty_ls_curve: 13-point stencil over eps + global reduction.
// R16 post-mortem: 8-waves/SIMD via 2-col ownership regressed (+50% bytes/
// output, 2x load insts). Reverted to R13 base (80.2us best).
// R15 re-read: VGPR_Count=64 + 365MB scratch => allocator picked the 64-reg
// class and spilled; depth-2 was never tested. The f2 mk() pair-packing
// (every Pz/dif is a 2-reg copy) caused the pressure, not the 10 row slots.
// R19: depth-2 with SCALAR math — 10-slot rotation (80 regs) + ~16 scalar
// temps ~= 108 < 128 cap, launch_bounds(256,4). Loads at phase p consumed at
// p+2 (~700 own-issue cycles + 3-wave cover vs ~900cyc HBM). Static schedule,
// overlap-masked last strip, frame on wave 0 — all carried from R13.

typedef float f4 __attribute__((ext_vector_type(4)));

constexpr float SCF = 1e-12f;
constexpr float EVF = 4.6415888336e-6f;        // 1e-32^(1/6)
constexpr float PID = 2.8559933214452666f;     // pi/1.1
constexpr float PIH = 1.5707963268f;
constexpr int   RS  = 64;                      // rows per strip
constexpr int   FT  = 40;                      // frame tasks per block

struct Row { f4 lo, hi; };                     // cols 4g..4g+3, 4g+4..4g+7

__device__ __forceinline__ float C(const Row& r, int k) {
    return k < 4 ? r.lo[k] : r.hi[k - 4];
}
__device__ __forceinline__ void load_row(Row& r, const float* p) {
    r.lo = *(const f4*)p;
    r.hi = *(const f4*)(p + 4);
}

// ---- scalar factored stencil for ONE output row; R0..R4 = rows i-2..i+2 ---
// c1 = inv2d ; c2 = 1e16 * inv2d^4
__device__ __forceinline__ float compute_row(const Row& R0, const Row& R1,
                                             const Row& R2, const Row& R3,
                                             const Row& R4,
                                             float c1, float c2) {
    float dif[6];                              // raw row diffs, cols j-1..j+4
    #pragma unroll
    for (int k = 0; k < 6; ++k)
        dif[k] = C(R3, k + 1) - C(R1, k + 1);

    float part = 0.0f;
    #pragma unroll
    for (int q = 0; q < 4; ++q) {
        const float c00  = C(R2, q + 2);
        const float u    = dif[q + 1];
        const float v    = C(R2, q + 3) - C(R2, q + 1);
        const float exxr = fmaf(-2.0f, c00, C(R4, q + 2) + C(R0, q + 2));
        const float eyyr = fmaf(-2.0f, c00, C(R2, q + 4) + C(R2, q));
        const float exyr = dif[q + 2] - dif[q];

        const float uu  = u * u;
        const float vv  = v * v;
        const float r2  = uu + vv;
        const float rsq = __builtin_amdgcn_rsqf(r2);
        const float N   = fmaf(uu, eyyr, fmaf(-2.0f * (u * v), exyr, vv * exxr));
        const float r3  = rsq * rsq * rsq;
        const float kabs = fabsf(N) * fminf(c1 * r3, c2);
        const float ev   = fmaxf(c1 * (r2 * rsq), EVF);   // NaN@r2=0 -> EVF

        const float aw = fabsf(c00 + 1e-6f);
        const float mx = fmaxf(ev, aw);
        const float mn = fminf(ev, aw);
        const float t  = mn * __builtin_amdgcn_rcpf(mx);
        const float t2 = t * t;
        float pl = fmaf(t2, -0.01172120f, 0.05265332f);
        pl = fmaf(t2, pl, -0.11643287f);
        pl = fmaf(t2, pl, 0.19354346f);
        pl = fmaf(t2, pl, -0.33262347f);
        pl = fmaf(t2, pl, 0.99997726f);
        pl *= t;
        const float at = (ev > aw) ? (PIH - pl) : pl;

        part += fmaxf(fmaf(kabs, at, -PID), 0.0f);  // fmax(NaN,0)=0 -> nansum
    }
    return part;
}

// ---- scalar tail (frame) ----
__device__ __forceinline__ float penalty_scalar(float ex, float ey, float exx,
                                                float exy, float eyy, float w) {
    const float ev = fmaxf(__builtin_amdgcn_sqrtf(fmaf(ex, ex, ey * ey)), EVF);
    const float num = fmaf(ex * ex, eyy, fmaf(-2.0f * ex * ey, exy, ey * ey * exx));
    const float kabs = fabsf(num) * __builtin_amdgcn_rcpf(ev * ev * ev);
    const float aw = fabsf(w + 1e-6f);
    const float mx = fmaxf(ev, aw);
    const float mn = fminf(ev, aw);
    const float t  = mn * __builtin_amdgcn_rcpf(mx);
    const float t2 = t * t;
    float pl = fmaf(t2, -0.01172120f, 0.05265332f);
    pl = fmaf(t2, pl, -0.11643287f);
    pl = fmaf(t2, pl, 0.19354346f);
    pl = fmaf(t2, pl, -0.33262347f);
    pl = fmaf(t2, pl, 0.99997726f);
    pl *= t;
    const float at = (ev > aw) ? (PIH - pl) : pl;
    return fmaxf(fmaf(kabs, at, -PID), 0.0f);
}

// ---- global-memory edge_order=1 gradients (frame) ----
__device__ __forceinline__ float eg(const float* __restrict__ e, int n, int i, int j) {
    return e[(size_t)i * (size_t)n + j];
}
__device__ __forceinline__ float gex(const float* __restrict__ e, int n, int i, int j,
                                     float inv_d, float inv_2d) {
    float v;
    if (i == 0)          v = (eg(e, n, 1, j) - eg(e, n, 0, j)) * inv_d;
    else if (i == n - 1) v = (eg(e, n, n - 1, j) - eg(e, n, n - 2, j)) * inv_d;
    else                 v = (eg(e, n, i + 1, j) - eg(e, n, i - 1, j)) * inv_2d;
    return v + SCF;
}
__device__ __forceinline__ float gey(const float* __restrict__ e, int n, int i, int j,
                                     float inv_d, float inv_2d) {
    float v;
    if (j == 0)          v = (eg(e, n, i, 1) - eg(e, n, i, 0)) * inv_d;
    else if (j == n - 1) v = (eg(e, n, i, n - 1) - eg(e, n, i, n - 2)) * inv_d;
    else                 v = (eg(e, n, i, j + 1) - eg(e, n, i, j - 1)) * inv_2d;
    return v + SCF;
}

__global__ __launch_bounds__(256, 4)
void fab_fused(const float* __restrict__ eps, const float* __restrict__ gs,
               float* __restrict__ ws, int n, int G2) {
    const float d      = *gs;
    const float inv_2d = 0.5f / d;
    const float inv_d  = inv_2d + inv_2d;
    const float c1     = inv_2d;
    const float c2     = 1e16f * (inv_2d * inv_2d) * (inv_2d * inv_2d);
    const int bflat    = blockIdx.y * gridDim.x + blockIdx.x;

    float acc = 0.0f;

    // ================== frame: 40 tasks/block on wave 0 ====================
    if (threadIdx.x < FT) {
        const int t = bflat * FT + (int)threadIdx.x;
        const int ntop = 4 * n;
        if (t < ntop) {
            const int rr = (t >= n) + (t >= 2 * n) + (t >= 3 * n);
            const int j = t - rr * n;
            const int i = (rr < 2) ? rr : (n - 4) + rr;

            const float ex0 = gex(eps, n, i, j, inv_d, inv_2d);
            const float ey0 = gey(eps, n, i, j, inv_d, inv_2d);
            float exx, exy, eyy;
            if (i == 0)
                exx = (gex(eps, n, 1, j, inv_d, inv_2d) - ex0) * inv_d;
            else if (i == n - 1)
                exx = (ex0 - gex(eps, n, n - 2, j, inv_d, inv_2d)) * inv_d;
            else
                exx = (gex(eps, n, i + 1, j, inv_d, inv_2d)
                     - gex(eps, n, i - 1, j, inv_d, inv_2d)) * inv_2d;
            if (j == 0)
                exy = (gex(eps, n, i, 1, inv_d, inv_2d) - ex0) * inv_d;
            else if (j == n - 1)
                exy = (ex0 - gex(eps, n, i, n - 2, inv_d, inv_2d)) * inv_d;
            else
                exy = (gex(eps, n, i, j + 1, inv_d, inv_2d)
                     - gex(eps, n, i, j - 1, inv_d, inv_2d)) * inv_2d;
            if (j == 0)
                eyy = (gey(eps, n, i, 1, inv_d, inv_2d) - ey0) * inv_d;
            else if (j == n - 1)
                eyy = (ey0 - gey(eps, n, i, n - 2, inv_d, inv_2d)) * inv_d;
            else
                eyy = (gey(eps, n, i, j + 1, inv_d, inv_2d)
                     - gey(eps, n, i, j - 1, inv_d, inv_2d)) * inv_2d;

            acc += penalty_scalar(ex0, ey0, exx, exy, eyy, eg(eps, n, i, j));
        } else if (t < ntop + (n - 4)) {
            // edge cols {0,1, n-6..n-1} of row i — 5x12 register window
            const int i = 2 + (t - ntop);
            float W[5][12];
            const float* rb = eps + (size_t)(i - 2) * (size_t)n;
            #pragma unroll
            for (int r = 0; r < 5; ++r) {
                const f4 a = *(const f4*)(rb + (size_t)r * n);
                const f4 b = *(const f4*)(rb + (size_t)r * n + (n - 8));
                const f4 c = *(const f4*)(rb + (size_t)r * n + (n - 4));
                #pragma unroll
                for (int k = 0; k < 4; ++k) {
                    W[r][k] = a[k]; W[r][4 + k] = b[k]; W[r][8 + k] = c[k];
                }
            }
            auto exW = [&](int r, int wc) {
                return (W[r + 1][wc] - W[r - 1][wc]) * inv_2d + SCF;
            };
            auto eyW = [&](int wc) {
                if (wc == 0)  return (W[2][1] - W[2][0]) * inv_d + SCF;
                if (wc == 11) return (W[2][11] - W[2][10]) * inv_d + SCF;
                return (W[2][wc + 1] - W[2][wc - 1]) * inv_2d + SCF;
            };
            #pragma unroll
            for (int m = 0; m < 8; ++m) {
                const int wc = (m < 2) ? m : m + 4;      // {0,1,6..11}
                const float ex0 = exW(2, wc);
                const float ey0 = eyW(wc);
                const float exx = (exW(3, wc) - exW(1, wc)) * inv_2d;
                float exy, eyy;
                if (wc == 0) {
                    exy = (exW(2, 1) - exW(2, 0)) * inv_d;
                    eyy = (eyW(1) - eyW(0)) * inv_d;
                } else if (wc == 11) {
                    exy = (exW(2, 11) - exW(2, 10)) * inv_d;
                    eyy = (eyW(11) - eyW(10)) * inv_d;
                } else {
                    exy = (exW(2, wc + 1) - exW(2, wc - 1)) * inv_2d;
                    eyy = (eyW(wc + 1) - eyW(wc - 1)) * inv_2d;
                }
                acc += penalty_scalar(ex0, ey0, exx, exy, eyy, W[2][wc]);
            }
        }
    }

    // == inner strip: static 32-phase pipeline, depth-2, scalar math ========
    {
        const int gg = blockIdx.x * 256 + threadIdx.x;
        const bool valid = gg < G2;
        const int gc = min(gg, G2 - 1);
        const int i0n = 2 + RS * (int)blockIdx.y;
        const int i0  = min(i0n, n - 2 - RS);          // last strip overlaps
        const float mA = (i0 == i0n) ? 1.0f : 0.0f;    // mask overlap phases
        const float* pj = eps + 4 * (size_t)gc;        // 16B-aligned windows
        const size_t sn = (size_t)n;

        // 10-slot rotation: slot(row r) = (r - (i0-2)) % 10.
        Row s0, s1, s2, s3, s4, s5, s6, s7, s8, s9;
        load_row(s0, pj + (size_t)(i0 - 2) * sn);
        load_row(s1, pj + (size_t)(i0 - 1) * sn);
        load_row(s2, pj + (size_t)(i0    ) * sn);
        load_row(s3, pj + (size_t)(i0 + 1) * sn);
        load_row(s4, pj + (size_t)(i0 + 2) * sn);
        load_row(s5, pj + (size_t)(i0 + 3) * sn);
        load_row(s6, pj + (size_t)(i0 + 4) * sn);
        load_row(s7, pj + (size_t)(i0 + 5) * sn);
        const float* pnext = pj + (size_t)(i0 + 6) * sn;

        float accs = 0.0f;

        // phase p: compute rows (i0+2p, i0+2p+1) from slots (2p..2p+5)%10;
        // load rows (i0+2p+6, i0+2p+7) into slots (2p+8, 2p+9)%10 — first
        // consumed at phase p+2. All loads unconditional (phases 0..29;
        // deepest row touched = i0+65 = n-1 by the overlap construction).
        #define PHL(A0, A1, A2, A3, A4, A5, L0, L1, M)                        \
        {                                                                     \
            load_row(L0, pnext);                                              \
            load_row(L1, pnext + sn);                                         \
            pnext += 2 * sn;                                                  \
            float ph = compute_row(A0, A1, A2, A3, A4, c1, c2)                \
                     + compute_row(A1, A2, A3, A4, A5, c1, c2);               \
            accs = fmaf((M), ph, accs);                                       \
        }

        // phases 0..4 (0,1 maskable for the overlapped last strip)
        PHL(s0, s1, s2, s3, s4, s5, s8, s9, mA)
        PHL(s2, s3, s4, s5, s6, s7, s0, s1, mA)
        PHL(s4, s5, s6, s7, s8, s9, s2, s3, 1.0f)
        PHL(s6, s7, s8, s9, s0, s1, s4, s5, 1.0f)
        PHL(s8, s9, s0, s1, s2, s3, s6, s7, 1.0f)
        // phases 5..29: five static iterations of the 5-phase rotation
        #pragma unroll 1
        for (int g = 0; g < 5; ++g) {
            PHL(s0, s1, s2, s3, s4, s5, s8, s9, 1.0f)
            PHL(s2, s3, s4, s5, s6, s7, s0, s1, 1.0f)
            PHL(s4, s5, s6, s7, s8, s9, s2, s3, 1.0f)
            PHL(s6, s7, s8, s9, s0, s1, s4, s5, 1.0f)
            PHL(s8, s9, s0, s1, s2, s3, s6, s7, 1.0f)
        }
        // phases 30, 31 peeled (compute only)
        accs += compute_row(s0, s1, s2, s3, s4, c1, c2)
              + compute_row(s1, s2, s3, s4, s5, c1, c2);
        accs += compute_row(s2, s3, s4, s5, s6, c1, c2)
              + compute_row(s3, s4, s5, s6, s7, c1, c2);
        #undef PHL

        if (valid) acc += accs;
    }

    // ---- reduction: wave -> block (LDS) -> unique ws slot ----
    __shared__ float wsum[4];
    #pragma unroll
    for (int off = 32; off; off >>= 1)
        acc += __shfl_down(acc, off, 64);
    if ((threadIdx.x & 63) == 0) wsum[threadIdx.x >> 6] = acc;
    __syncthreads();
    if (threadIdx.x == 0)
        ws[bflat] = wsum[0] + wsum[1] + wsum[2] + wsum[3];
}

__global__ __launch_bounds__(256)
void fab_finish(const float* __restrict__ ws, const float* __restrict__ gs,
                float* __restrict__ out, int nb) {
    __shared__ float wsum[4];
    float v = 0.0f;
    for (int i = threadIdx.x; i < nb; i += 256) v += ws[i];
    #pragma unroll
    for (int off = 32; off; off >>= 1)
        v += __shfl_down(v, off, 64);
    if ((threadIdx.x & 63) == 0) wsum[threadIdx.x >> 6] = v;
    __syncthreads();
    if (threadIdx.x == 0) {
        const float d = *gs;
        out[0] = (wsum[0] + wsum[1] + wsum[2] + wsum[3]) * d * d;
    }
}

extern "C" void kernel_launch(void* const* d_in, const int* in_sizes, int n_in,
                              void* d_out, int out_size, void* d_ws, size_t ws_size,
                              hipStream_t stream) {
    const float* eps = (const float*)d_in[0];
    const float* gs  = (const float*)d_in[1];
    float* out = (float*)d_out;
    float* ws  = (float*)d_ws;

    const long long tot = (long long)in_sizes[0];
    const int n = (int)(sqrt((double)tot) + 0.5);   // 8192

    const int G2 = (n - 8) / 4;                     // interior col groups
    const int nstrip = (n - 4 + RS - 1) / RS;       // 128

    dim3 block(256, 1);
    dim3 grid(n / 1024, nstrip);                    // 8 x 128 = 1024 blocks
    fab_fused<<<grid, block, 0, stream>>>(eps, gs, ws, n, G2);
    fab_finish<<<1, 256, 0, stream>>>(ws, gs, out, grid.x * grid.y);
}

// Round 21
// 75.954 us; speedup vs baseline: 1.3935x; 1.3935x over previous
//
#include <hip/hip_runtime.h>
#include <math.h>

// Fused fab_penalty_ls_curve: 13-point stencil over eps + global reduction.
// FINAL REVERT to R13 (measured best: 80.2us) after depth-2 falsified 3x
// (R6 98.7 / R15 259-spill / R19 105.8) and occupancy/stagger/alignment all
// null. Structure: 128-col 4-per-thread ownership, 8-slot register rotation,
// FULLY STATIC unconditional load schedule (the +6% lever: compiler can emit
// counted vmcnt instead of vmcnt(0) drains), overlap-masked last strip,
// packed-f2 factored math (c1/c2 scaling), coalesced frame on wave 0,
// 1024 blocks = 4/CU capacity, ws-slot partials + tiny finisher.

typedef float f2 __attribute__((ext_vector_type(2)));
typedef float f4 __attribute__((ext_vector_type(4)));

constexpr float SCF = 1e-12f;
constexpr float EVF = 4.6415888336e-6f;        // 1e-32^(1/6)
constexpr float PID = 2.8559933214452666f;     // pi/1.1
constexpr float PIH = 1.5707963268f;
constexpr int   RS  = 64;                      // rows per strip
constexpr int   FT  = 40;                      // frame tasks per block

struct Row { f4 lo, hi; };                     // cols 4g..4g+3, 4g+4..4g+7

__device__ __forceinline__ float C(const Row& r, int k) {
    return k < 4 ? r.lo[k] : r.hi[k - 4];
}
__device__ __forceinline__ void load_row(Row& r, const float* p) {
    r.lo = *(const f4*)p;
    r.hi = *(const f4*)(p + 4);
}
__device__ __forceinline__ f2 mk(float a, float b) { f2 v; v.x = a; v.y = b; return v; }
__device__ __forceinline__ f2 fma2(f2 a, f2 b, f2 c) { return __builtin_elementwise_fma(a, b, c); }
__device__ __forceinline__ f2 max2(f2 a, f2 b) { return __builtin_elementwise_max(a, b); }
__device__ __forceinline__ f2 min2(f2 a, f2 b) { return __builtin_elementwise_min(a, b); }
__device__ __forceinline__ f2 abs2(f2 a) { return __builtin_elementwise_abs(a); }
__device__ __forceinline__ f2 rcp2(f2 a) {
    return mk(__builtin_amdgcn_rcpf(a.x), __builtin_amdgcn_rcpf(a.y));
}
__device__ __forceinline__ f2 rsq2(f2 a) {
    return mk(__builtin_amdgcn_rsqf(a.x), __builtin_amdgcn_rsqf(a.y));
}

// ---- packed factored math for output rows (i,i+1): R0..R5 = rows i-2..i+3
// c1 = inv2d ; c2 = 1e16 * inv2d^4
__device__ __forceinline__ f2 compute_pair(const Row& R0, const Row& R1,
                                           const Row& R2, const Row& R3,
                                           const Row& R4, const Row& R5,
                                           f2 c1, f2 c2) {
    f2 dif[6];
    #pragma unroll
    for (int k = 0; k < 6; ++k)
        dif[k] = mk(C(R3, k + 1) - C(R1, k + 1),
                    C(R4, k + 1) - C(R2, k + 1));
    f2 Pz[8];
    #pragma unroll
    for (int k = 0; k < 8; ++k)
        Pz[k] = mk(C(R2, k), C(R3, k));

    f2 part = mk(0.0f, 0.0f);
    #pragma unroll
    for (int q = 0; q < 4; ++q) {
        const f2 c00  = Pz[q + 2];
        const f2 u    = dif[q + 1];
        const f2 v    = Pz[q + 3] - Pz[q + 1];
        const f2 exxr = fma2(mk(-2.0f, -2.0f), c00,
                             mk(C(R4, q + 2) + C(R0, q + 2),
                                C(R5, q + 2) + C(R1, q + 2)));
        const f2 eyyr = fma2(mk(-2.0f, -2.0f), c00, Pz[q + 4] + Pz[q]);
        const f2 exyr = dif[q + 2] - dif[q];

        const f2 uu  = u * u;
        const f2 vv  = v * v;
        const f2 r2  = uu + vv;
        const f2 rsq = rsq2(r2);
        const f2 N   = fma2(uu, eyyr, fma2(-2.0f * (u * v), exyr, vv * exxr));
        const f2 r3  = rsq * rsq * rsq;
        const f2 kabs = abs2(N) * min2(c1 * r3, c2);
        const f2 ev   = max2(c1 * (r2 * rsq), mk(EVF, EVF));

        const f2 aw = abs2(c00 + 1e-6f);
        const f2 mx = max2(ev, aw);
        const f2 mn = min2(ev, aw);
        const f2 t  = mn * rcp2(mx);
        const f2 t2 = t * t;
        f2 pl = fma2(t2, mk(-0.01172120f, -0.01172120f), mk(0.05265332f, 0.05265332f));
        pl = fma2(t2, pl, mk(-0.11643287f, -0.11643287f));
        pl = fma2(t2, pl, mk(0.19354346f, 0.19354346f));
        pl = fma2(t2, pl, mk(-0.33262347f, -0.33262347f));
        pl = fma2(t2, pl, mk(0.99997726f, 0.99997726f));
        pl = pl * t;
        f2 at;
        at.x = (ev.x > aw.x) ? PIH - pl.x : pl.x;
        at.y = (ev.y > aw.y) ? PIH - pl.y : pl.y;

        part = part + max2(fma2(kabs, at, mk(-PID, -PID)), mk(0.0f, 0.0f));
    }
    return part;
}

// ---- scalar tail (frame) ----
__device__ __forceinline__ float penalty_scalar(float ex, float ey, float exx,
                                                float exy, float eyy, float w) {
    const float ev = fmaxf(__builtin_amdgcn_sqrtf(fmaf(ex, ex, ey * ey)), EVF);
    const float num = fmaf(ex * ex, eyy, fmaf(-2.0f * ex * ey, exy, ey * ey * exx));
    const float kabs = fabsf(num) * __builtin_amdgcn_rcpf(ev * ev * ev);
    const float aw = fabsf(w + 1e-6f);
    const float mx = fmaxf(ev, aw);
    const float mn = fminf(ev, aw);
    const float t  = mn * __builtin_amdgcn_rcpf(mx);
    const float t2 = t * t;
    float pl = fmaf(t2, -0.01172120f, 0.05265332f);
    pl = fmaf(t2, pl, -0.11643287f);
    pl = fmaf(t2, pl, 0.19354346f);
    pl = fmaf(t2, pl, -0.33262347f);
    pl = fmaf(t2, pl, 0.99997726f);
    pl *= t;
    const float at = (ev > aw) ? (PIH - pl) : pl;
    return fmaxf(fmaf(kabs, at, -PID), 0.0f);
}

// ---- global-memory edge_order=1 gradients (frame) ----
__device__ __forceinline__ float eg(const float* __restrict__ e, int n, int i, int j) {
    return e[(size_t)i * (size_t)n + j];
}
__device__ __forceinline__ float gex(const float* __restrict__ e, int n, int i, int j,
                                     float inv_d, float inv_2d) {
    float v;
    if (i == 0)          v = (eg(e, n, 1, j) - eg(e, n, 0, j)) * inv_d;
    else if (i == n - 1) v = (eg(e, n, n - 1, j) - eg(e, n, n - 2, j)) * inv_d;
    else                 v = (eg(e, n, i + 1, j) - eg(e, n, i - 1, j)) * inv_2d;
    return v + SCF;
}
__device__ __forceinline__ float gey(const float* __restrict__ e, int n, int i, int j,
                                     float inv_d, float inv_2d) {
    float v;
    if (j == 0)          v = (eg(e, n, i, 1) - eg(e, n, i, 0)) * inv_d;
    else if (j == n - 1) v = (eg(e, n, i, n - 1) - eg(e, n, i, n - 2)) * inv_d;
    else                 v = (eg(e, n, i, j + 1) - eg(e, n, i, j - 1)) * inv_2d;
    return v + SCF;
}

__global__ __launch_bounds__(256, 4)
void fab_fused(const float* __restrict__ eps, const float* __restrict__ gs,
               float* __restrict__ ws, int n, int G2) {
    const float d      = *gs;
    const float inv_2d = 0.5f / d;
    const float inv_d  = inv_2d + inv_2d;
    const float c1s    = inv_2d;
    const float c2s    = 1e16f * (inv_2d * inv_2d) * (inv_2d * inv_2d);
    const int bflat    = blockIdx.y * gridDim.x + blockIdx.x;

    float acc = 0.0f;

    // ================== frame: 40 tasks/block on wave 0 ====================
    if (threadIdx.x < FT) {
        const int t = bflat * FT + (int)threadIdx.x;
        const int ntop = 4 * n;
        if (t < ntop) {
            const int rr = (t >= n) + (t >= 2 * n) + (t >= 3 * n);
            const int j = t - rr * n;
            const int i = (rr < 2) ? rr : (n - 4) + rr;

            const float ex0 = gex(eps, n, i, j, inv_d, inv_2d);
            const float ey0 = gey(eps, n, i, j, inv_d, inv_2d);
            float exx, exy, eyy;
            if (i == 0)
                exx = (gex(eps, n, 1, j, inv_d, inv_2d) - ex0) * inv_d;
            else if (i == n - 1)
                exx = (ex0 - gex(eps, n, n - 2, j, inv_d, inv_2d)) * inv_d;
            else
                exx = (gex(eps, n, i + 1, j, inv_d, inv_2d)
                     - gex(eps, n, i - 1, j, inv_d, inv_2d)) * inv_2d;
            if (j == 0)
                exy = (gex(eps, n, i, 1, inv_d, inv_2d) - ex0) * inv_d;
            else if (j == n - 1)
                exy = (ex0 - gex(eps, n, i, n - 2, inv_d, inv_2d)) * inv_d;
            else
                exy = (gex(eps, n, i, j + 1, inv_d, inv_2d)
                     - gex(eps, n, i, j - 1, inv_d, inv_2d)) * inv_2d;
            if (j == 0)
                eyy = (gey(eps, n, i, 1, inv_d, inv_2d) - ey0) * inv_d;
            else if (j == n - 1)
                eyy = (ey0 - gey(eps, n, i, n - 2, inv_d, inv_2d)) * inv_d;
            else
                eyy = (gey(eps, n, i, j + 1, inv_d, inv_2d)
                     - gey(eps, n, i, j - 1, inv_d, inv_2d)) * inv_2d;

            acc += penalty_scalar(ex0, ey0, exx, exy, eyy, eg(eps, n, i, j));
        } else if (t < ntop + (n - 4)) {
            // edge cols {0,1, n-6..n-1} of row i — 5x12 register window
            const int i = 2 + (t - ntop);
            float W[5][12];
            const float* rb = eps + (size_t)(i - 2) * (size_t)n;
            #pragma unroll
            for (int r = 0; r < 5; ++r) {
                const f4 a = *(const f4*)(rb + (size_t)r * n);
                const f4 b = *(const f4*)(rb + (size_t)r * n + (n - 8));
                const f4 c = *(const f4*)(rb + (size_t)r * n + (n - 4));
                #pragma unroll
                for (int k = 0; k < 4; ++k) {
                    W[r][k] = a[k]; W[r][4 + k] = b[k]; W[r][8 + k] = c[k];
                }
            }
            auto exW = [&](int r, int wc) {
                return (W[r + 1][wc] - W[r - 1][wc]) * inv_2d + SCF;
            };
            auto eyW = [&](int wc) {
                if (wc == 0)  return (W[2][1] - W[2][0]) * inv_d + SCF;
                if (wc == 11) return (W[2][11] - W[2][10]) * inv_d + SCF;
                return (W[2][wc + 1] - W[2][wc - 1]) * inv_2d + SCF;
            };
            #pragma unroll
            for (int m = 0; m < 8; ++m) {
                const int wc = (m < 2) ? m : m + 4;      // {0,1,6..11}
                const float ex0 = exW(2, wc);
                const float ey0 = eyW(wc);
                const float exx = (exW(3, wc) - exW(1, wc)) * inv_2d;
                float exy, eyy;
                if (wc == 0) {
                    exy = (exW(2, 1) - exW(2, 0)) * inv_d;
                    eyy = (eyW(1) - eyW(0)) * inv_d;
                } else if (wc == 11) {
                    exy = (exW(2, 11) - exW(2, 10)) * inv_d;
                    eyy = (eyW(11) - eyW(10)) * inv_d;
                } else {
                    exy = (exW(2, wc + 1) - exW(2, wc - 1)) * inv_2d;
                    eyy = (eyW(wc + 1) - eyW(wc - 1)) * inv_2d;
                }
                acc += penalty_scalar(ex0, ey0, exx, exy, eyy, W[2][wc]);
            }
        }
    }

    // ============ inner strip: fully static 32-phase pipeline ==============
    {
        const int gg = blockIdx.x * 256 + threadIdx.x;
        const bool valid = gg < G2;
        const int gc = min(gg, G2 - 1);
        const int i0n = 2 + RS * (int)blockIdx.y;
        const int i0  = min(i0n, n - 2 - RS);          // last strip overlaps
        const float mA = (i0 == i0n) ? 1.0f : 0.0f;    // mask overlap phases
        const float* pj = eps + 4 * (size_t)gc;        // 16B-aligned windows
        const size_t sn = (size_t)n;
        const f2 c1 = mk(c1s, c1s);
        const f2 c2 = mk(c2s, c2s);
        const f2 m2 = mk(mA, mA);

        Row s0, s1, s2, s3, s4, s5, s6, s7;
        load_row(s0, pj + (size_t)(i0 - 2) * sn);
        load_row(s1, pj + (size_t)(i0 - 1) * sn);
        load_row(s2, pj + (size_t)(i0    ) * sn);
        load_row(s3, pj + (size_t)(i0 + 1) * sn);
        load_row(s4, pj + (size_t)(i0 + 2) * sn);
        load_row(s5, pj + (size_t)(i0 + 3) * sn);
        const float* pnext = pj + (size_t)(i0 + 4) * sn;

        f2 acc2 = mk(0.0f, 0.0f);

        // phase ph (0..31): compute rows (i0+2ph, i0+2ph+1); phases 0..30
        // also load rows (i0+2ph+4, i0+2ph+5) — all unconditional.
        #define PHL(A0, A1, A2, A3, A4, A5, L0, L1, M)                        \
        {                                                                     \
            load_row(L0, pnext);                                              \
            load_row(L1, pnext + sn);                                         \
            pnext += 2 * sn;                                                  \
            acc2 = acc2 + (M) * compute_pair(A0, A1, A2, A3, A4, A5, c1, c2); \
        }
        const f2 one2 = mk(1.0f, 1.0f);

        // phases 0,1 (maskable), 2,3
        PHL(s0, s1, s2, s3, s4, s5, s6, s7, m2)
        PHL(s2, s3, s4, s5, s6, s7, s0, s1, m2)
        PHL(s4, s5, s6, s7, s0, s1, s2, s3, one2)
        PHL(s6, s7, s0, s1, s2, s3, s4, s5, one2)
        // phases 4..27: six static iterations of the 4-phase rotation
        #pragma unroll 1
        for (int g = 0; g < 6; ++g) {
            PHL(s0, s1, s2, s3, s4, s5, s6, s7, one2)
            PHL(s2, s3, s4, s5, s6, s7, s0, s1, one2)
            PHL(s4, s5, s6, s7, s0, s1, s2, s3, one2)
            PHL(s6, s7, s0, s1, s2, s3, s4, s5, one2)
        }
        // phases 28,29,30 (with loads), 31 peeled (compute only)
        PHL(s0, s1, s2, s3, s4, s5, s6, s7, one2)
        PHL(s2, s3, s4, s5, s6, s7, s0, s1, one2)
        PHL(s4, s5, s6, s7, s0, s1, s2, s3, one2)
        acc2 = acc2 + compute_pair(s6, s7, s0, s1, s2, s3, c1, c2);
        #undef PHL

        if (valid) acc += acc2.x + acc2.y;
    }

    // ---- reduction: wave -> block (LDS) -> unique ws slot ----
    __shared__ float wsum[4];
    #pragma unroll
    for (int off = 32; off; off >>= 1)
        acc += __shfl_down(acc, off, 64);
    if ((threadIdx.x & 63) == 0) wsum[threadIdx.x >> 6] = acc;
    __syncthreads();
    if (threadIdx.x == 0)
        ws[bflat] = wsum[0] + wsum[1] + wsum[2] + wsum[3];
}

__global__ __launch_bounds__(256)
void fab_finish(const float* __restrict__ ws, const float* __restrict__ gs,
                float* __restrict__ out, int nb) {
    __shared__ float wsum[4];
    float v = 0.0f;
    for (int i = threadIdx.x; i < nb; i += 256) v += ws[i];
    #pragma unroll
    for (int off = 32; off; off >>= 1)
        v += __shfl_down(v, off, 64);
    if ((threadIdx.x & 63) == 0) wsum[threadIdx.x >> 6] = v;
    __syncthreads();
    if (threadIdx.x == 0) {
        const float d = *gs;
        out[0] = (wsum[0] + wsum[1] + wsum[2] + wsum[3]) * d * d;
    }
}

extern "C" void kernel_launch(void* const* d_in, const int* in_sizes, int n_in,
                              void* d_out, int out_size, void* d_ws, size_t ws_size,
                              hipStream_t stream) {
    const float* eps = (const float*)d_in[0];
    const float* gs  = (const float*)d_in[1];
    float* out = (float*)d_out;
    float* ws  = (float*)d_ws;

    const long long tot = (long long)in_sizes[0];
    const int n = (int)(sqrt((double)tot) + 0.5);   // 8192

    const int G2 = (n - 8) / 4;                     // interior col groups
    const int nstrip = (n - 4 + RS - 1) / RS;       // 128

    dim3 block(256, 1);
    dim3 grid(n / 1024, nstrip);                    // 8 x 128 = 1024 blocks
    fab_fused<<<grid, block, 0, stream>>>(eps, gs, ws, n, G2);
    fab_finish<<<1, 256, 0, stream>>>(ws, gs, out, grid.x * grid.y);
}